// Round 5
// baseline (1550.886 us; speedup 1.0000x reference)
//
#include <hip/hip_runtime.h>
#include <hip/hip_bf16.h>

constexpr int kN    = 100000;
constexpr int kE    = 1600000;
constexpr int kD    = 64;
constexpr int kNF   = 9;
constexpr int kCARD = 16;
constexpr int kBF   = 16;
constexpr int kScanBlocks = (kN + 1023) / 1024;  // 98

typedef __bf16 bf16x8 __attribute__((ext_vector_type(8)));
typedef float f32x4 __attribute__((ext_vector_type(4)));
union U4BF { uint4 u; bf16x8 v; };

__device__ __forceinline__ float lane_bcast(float v, int k) {
  return __uint_as_float((unsigned)__builtin_amdgcn_readlane((int)__float_as_uint(v), k));
}
__device__ __forceinline__ float sigm(float v) { return 1.f / (1.f + __expf(-v)); }
__device__ __forceinline__ float tanh_f(float v) { return 1.f - 2.f / (__expf(2.f * v) + 1.f); }

__device__ __forceinline__ unsigned bf16_bits(float v) {
  unsigned u = __float_as_uint(v);
  return (u + 0x7fffu + ((u >> 16) & 1u)) >> 16;
}
__device__ __forceinline__ unsigned pack_bf(float lo, float hi) {
  return bf16_bits(lo) | (bf16_bits(hi) << 16);
}
__device__ __forceinline__ float bflo(unsigned u) { return __uint_as_float(u << 16); }
__device__ __forceinline__ float bfhi(unsigned u) { return __uint_as_float(u & 0xffff0000u); }

// ---------- degree counts (row for deg/dinv, col for CSR) ----------
__global__ void k_cnt(const int* __restrict__ row, const int* __restrict__ col,
                      int* __restrict__ cntr, int* __restrict__ cntc) {
  int e = blockIdx.x * blockDim.x + threadIdx.x;
  if (e < kE) {
    atomicAdd(&cntr[row[e]], 1);
    atomicAdd(&cntc[col[e]], 1);
  }
}

__global__ void k_dinv(const int* __restrict__ cnt, float* __restrict__ degf,
                       float* __restrict__ dinv) {
  int n = blockIdx.x * blockDim.x + threadIdx.x;
  if (n < kN) {
    float d = (float)cnt[n] + 1.f;
    degf[n] = d;
    dinv[n] = rsqrtf(d);
  }
}

// ---------- multi-block exclusive scan of col counts ----------
__global__ __launch_bounds__(1024) void k_scanA(const int* __restrict__ cnt,
                                                int* __restrict__ loc,
                                                int* __restrict__ bsum) {
  __shared__ int part[1024];
  int tid = threadIdx.x;
  int i = blockIdx.x * 1024 + tid;
  int v = (i < kN) ? cnt[i] : 0;
  part[tid] = v;
  __syncthreads();
  for (int off = 1; off < 1024; off <<= 1) {
    int t = (tid >= off) ? part[tid - off] : 0;
    __syncthreads();
    part[tid] += t;
    __syncthreads();
  }
  if (i < kN) loc[i] = part[tid] - v;  // local exclusive
  if (tid == 1023) bsum[blockIdx.x] = part[1023];
}

__global__ __launch_bounds__(128) void k_scanB(const int* __restrict__ bsum,
                                               int* __restrict__ boff) {
  __shared__ int p[128];
  int tid = threadIdx.x;
  int v = (tid < kScanBlocks) ? bsum[tid] : 0;
  p[tid] = v;
  __syncthreads();
  for (int off = 1; off < 128; off <<= 1) {
    int t = (tid >= off) ? p[tid - off] : 0;
    __syncthreads();
    p[tid] += t;
    __syncthreads();
  }
  boff[tid] = p[tid] - v;  // exclusive
}

__global__ __launch_bounds__(1024) void k_scanC(const int* __restrict__ loc,
                                                const int* __restrict__ boff,
                                                int* __restrict__ ptr,
                                                int* __restrict__ fill) {
  int i = blockIdx.x * 1024 + threadIdx.x;
  if (i < kN) {
    int v = loc[i] + boff[blockIdx.x];
    ptr[i] = v;
    fill[i] = v;
  }
  if (i == 0) ptr[kN] = kE;  // grand total is statically kE
}

// ---------- scatter (row, eid) + norm into col-sorted order ----------
__global__ void k_scatter(const int* __restrict__ row, const int* __restrict__ col,
                          const float* __restrict__ dinv, int* __restrict__ fill,
                          int2* __restrict__ re, float* __restrict__ nrm) {
  int e = blockIdx.x * blockDim.x + threadIdx.x;
  if (e < kE) {
    int r = row[e], c = col[e];
    int p = atomicAdd(&fill[c], 1);
    re[p] = make_int2(r, e);
    nrm[p] = dinv[r] * dinv[c];
  }
}

// ---------- reorder edge_attr into CSR order as bf16 (16 thr/edge) ----------
__global__ void k_gea(const int2* __restrict__ re, const float* __restrict__ ea,
                      unsigned short* __restrict__ ea_s) {
  int idx = blockIdx.x * 256 + threadIdx.x;
  int p = idx >> 4, c = idx & 15;
  if (p < kE) {
    int e = re[p].y;
    ea_s[(size_t)p * 16 + c] = (unsigned short)bf16_bits(ea[(size_t)e * 16 + c]);
  }
}

// ---------- edge_attr moments: sumA[16], M = A^T A [16x16] ----------
__global__ __launch_bounds__(256) void k_stats(const float* __restrict__ ea,
                                               float* __restrict__ sumA,
                                               float* __restrict__ Msum) {
  __shared__ float tile[1024];
  int tid = threadIdx.x;
  int i = tid >> 4, j = tid & 15;
  float accM = 0.f, accS = 0.f;
  const int T = kE / 64;
  for (int t = blockIdx.x; t < T; t += gridDim.x) {
    const float4* src = (const float4*)(ea + (size_t)t * 1024);
    ((float4*)tile)[tid] = src[tid];
    __syncthreads();
#pragma unroll 8
    for (int e = 0; e < 64; e++) {
      float aj = tile[e * 16 + j];
      accM += tile[e * 16 + i] * aj;
      if (i == 0) accS += aj;
    }
    __syncthreads();
  }
  atomicAdd(&Msum[i * 16 + j], accM);
  if (i == 0) atomicAdd(&sumA[j], accS);
}

// ---------- fold bond-linear + BN into Weff/beff per layer ----------
__global__ __launch_bounds__(256) void k_bnfold(
    const float* __restrict__ sumA, const float* __restrict__ Msum,
    const float* __restrict__ bond_W, const float* __restrict__ bond_b,
    const float* __restrict__ bond_g, const float* __restrict__ bond_beta,
    float* __restrict__ Weff, float* __restrict__ beff) {
  __shared__ float Ms[256];
  __shared__ float ab[16];
  int tid = threadIdx.x;
  Ms[tid] = Msum[tid] * (1.f / (float)kE);
  if (tid < 16) ab[tid] = sumA[tid] * (1.f / (float)kE);
  __syncthreads();
  if (tid < 192) {
    int l = tid / 64, d = tid % 64;
    const float* W = bond_W + l * kBF * kD;
    float w[16];
#pragma unroll
    for (int k = 0; k < 16; k++) w[k] = W[k * 64 + d];
    float b = bond_b[l * 64 + d];
    float lin = 0.f;
#pragma unroll
    for (int k = 0; k < 16; k++) lin += ab[k] * w[k];
    float mu = lin + b;
    float q = 0.f;
#pragma unroll
    for (int i = 0; i < 16; i++) {
      float wi = w[i];
#pragma unroll
      for (int k = 0; k < 16; k++) q += Ms[i * 16 + k] * wi * w[k];
    }
    float ex2 = q + 2.f * b * lin + b * b;
    float var = ex2 - mu * mu;
    float s = bond_g[l * 64 + d] * rsqrtf(var + 1e-6f);
#pragma unroll
    for (int k = 0; k < 16; k++) Weff[l * 1024 + k * 64 + d] = w[k] * s;
    beff[l * 64 + d] = (b - mu) * s + bond_beta[l * 64 + d];
  }
}

// ---------- GRU weight prep: Bt[l][j][k] bf16, j in [0,256), k in [0,128) ----------
__global__ void k_wprep(const float* __restrict__ Wih, const float* __restrict__ Whh,
                        unsigned short* __restrict__ Bt) {
  int idx = blockIdx.x * 256 + threadIdx.x;
  if (idx >= 3 * 256 * 128) return;
  int l = idx / (256 * 128);
  int rem = idx % (256 * 128);
  int j = rem / 128, k = rem % 128;
  const float* ih = Wih + l * 192 * 64;
  const float* hh = Whh + l * 192 * 64;
  float v;
  if (j < 128)      v = (k < 64) ? ih[j * 64 + k] : hh[j * 64 + (k - 64)];
  else if (j < 192) v = (k < 64) ? ih[j * 64 + k] : 0.f;
  else              v = (k < 64) ? 0.f : hh[(j - 64) * 64 + (k - 64)];
  Bt[idx] = (unsigned short)bf16_bits(v);
}

// ---------- encoder: h = [atom_x, sum_f emb] @ projW + b ----------
__global__ __launch_bounds__(256) void k_enc(
    const float* __restrict__ atom_x, const int* __restrict__ feat,
    const float* __restrict__ emb, const float* __restrict__ projW,
    const float* __restrict__ projb, float* __restrict__ h) {
  __shared__ float W[128 * 64];
  int tid = threadIdx.x;
  for (int i = tid; i < 128 * 64 / 4; i += 256)
    ((float4*)W)[i] = ((const float4*)projW)[i];
  __syncthreads();
  int lane = tid & 63, wv = tid >> 6;
  int gw = blockIdx.x * 4 + wv, nw = gridDim.x * 4;
  float bd = projb[lane];
  for (int grp = gw; grp < kN / 4; grp += nw) {
    int n0 = grp * 4;
    float ax[4], x2[4], acc[4];
#pragma unroll
    for (int i = 0; i < 4; i++) {
      int n = n0 + i;
      ax[i] = atom_x[n * kD + lane];
      const int* fr = feat + n * kNF;
      float s = 0.f;
#pragma unroll
      for (int f = 0; f < kNF; f++) {
        int c = fr[f];
        s += emb[(f * kCARD + c) * kD + lane];
      }
      x2[i] = s;
      acc[i] = bd;
    }
#pragma unroll 4
    for (int k = 0; k < kD; k++) {
      float wt = W[k * 64 + lane];
      float wb = W[(64 + k) * 64 + lane];
#pragma unroll
      for (int i = 0; i < 4; i++)
        acc[i] += lane_bcast(ax[i], k) * wt + lane_bcast(x2[i], k) * wb;
    }
#pragma unroll
    for (int i = 0; i < 4; i++) h[(n0 + i) * kD + lane] = acc[i];
  }
}

// ---------- x = BN(h)[opt relu] @ lin_W + lin_b ; writes fp32 x and bf16 xb ----------
__global__ __launch_bounds__(256) void k_lin(
    const float* __restrict__ hin, const float* __restrict__ Wg,
    const float* __restrict__ bg, int apply_bn,
    const float* __restrict__ bnsum, const float* __restrict__ bnss,
    const float* __restrict__ bng, const float* __restrict__ bnb,
    float* __restrict__ xout, unsigned short* __restrict__ xb) {
  __shared__ float W[64 * 64];
  int tid = threadIdx.x;
  for (int i = tid; i < 64 * 64 / 4; i += 256)
    ((float4*)W)[i] = ((const float4*)Wg)[i];
  __syncthreads();
  int lane = tid & 63, wv = tid >> 6;
  int gw = blockIdx.x * 4 + wv, nw = gridDim.x * 4;
  float mu = 0.f, sc = 0.f, bb = 0.f;
  if (apply_bn) {
    float m = bnsum[lane] * (1.f / (float)kN);
    float var = bnss[lane] * (1.f / (float)kN) - m * m;
    mu = m;
    sc = rsqrtf(var + 1e-5f) * bng[lane];
    bb = bnb[lane];
  }
  float bd = bg[lane];
  for (int grp = gw; grp < kN / 4; grp += nw) {
    int n0 = grp * 4;
    float hv[4], acc[4];
#pragma unroll
    for (int i = 0; i < 4; i++) {
      float v = hin[(n0 + i) * kD + lane];
      if (apply_bn) v = fmaxf((v - mu) * sc + bb, 0.f);
      hv[i] = v;
      acc[i] = bd;
    }
#pragma unroll 4
    for (int k = 0; k < kD; k++) {
      float w = W[k * 64 + lane];
#pragma unroll
      for (int i = 0; i < 4; i++) acc[i] += lane_bcast(hv[i], k) * w;
    }
#pragma unroll
    for (int i = 0; i < 4; i++) {
      xout[(n0 + i) * kD + lane] = acc[i];
      xb[(size_t)(n0 + i) * kD + lane] = (unsigned short)bf16_bits(acc[i]);
    }
  }
}

// ---------- CSR gather: aggr_b[n] = bf16( sum_e nrm*relu(xb[row]+bond) ) ----------
__global__ __launch_bounds__(256) void k_aggr(
    const int* __restrict__ ptr, const int2* __restrict__ re,
    const float* __restrict__ nrm, const unsigned short* __restrict__ ea_s,
    const unsigned short* __restrict__ xb, const float* __restrict__ Weff,
    const float* __restrict__ beff, unsigned short* __restrict__ aggr_b) {
  int lane = threadIdx.x & 63, wv = threadIdx.x >> 6;
  int n = blockIdx.x * 4 + wv;
  if (n >= kN) return;
  float wc[16];
#pragma unroll
  for (int k = 0; k < 16; k++) wc[k] = Weff[k * 64 + lane];
  float be = beff[lane];
  int start = ptr[n], end = ptr[n + 1];
  float acc = 0.f;
  for (int j0 = start; j0 < end; j0 += 64) {
    int j = j0 + lane;
    bool val = j < end;
    int2 m = val ? re[j] : make_int2(0, 0);
    float nr = val ? nrm[j] : 0.f;
    int cnt = min(64, end - j0);
#pragma unroll 2
    for (int t = 0; t < cnt; t++) {
      int rt = __builtin_amdgcn_readlane(m.x, t);
      float nv = lane_bcast(nr, t);
      const uint4* ap = (const uint4*)(ea_s + (size_t)(j0 + t) * 16);
      uint4 a0 = ap[0];
      uint4 a1 = ap[1];
      float xv = __uint_as_float(((unsigned)xb[(size_t)rt * kD + lane]) << 16);
      float bond = be;
      bond += bflo(a0.x) * wc[0] + bfhi(a0.x) * wc[1];
      bond += bflo(a0.y) * wc[2] + bfhi(a0.y) * wc[3];
      bond += bflo(a0.z) * wc[4] + bfhi(a0.z) * wc[5];
      bond += bflo(a0.w) * wc[6] + bfhi(a0.w) * wc[7];
      bond += bflo(a1.x) * wc[8] + bfhi(a1.x) * wc[9];
      bond += bflo(a1.y) * wc[10] + bfhi(a1.y) * wc[11];
      bond += bflo(a1.z) * wc[12] + bfhi(a1.z) * wc[13];
      bond += bflo(a1.w) * wc[14] + bfhi(a1.w) * wc[15];
      acc += nv * fmaxf(xv + bond, 0.f);
    }
  }
  aggr_b[(size_t)n * kD + lane] = (unsigned short)bf16_bits(acc);
}

// ---------- MFMA GRU: [64-node,128] @ [128,256] per block + fused epilogue ----------
__global__ __launch_bounds__(256) void k_gru_mfma(
    const unsigned short* __restrict__ aggr_b, const unsigned short* __restrict__ xb,
    const float* __restrict__ x, const unsigned short* __restrict__ Bt,
    const float* __restrict__ bih, const float* __restrict__ bhh,
    const float* __restrict__ root, const float* __restrict__ degf,
    float* __restrict__ h, float* __restrict__ bnsum, float* __restrict__ bnss) {
  __shared__ float sb[2][16][65];
  int tid = threadIdx.x;
  int wv = tid >> 6;
  int c = tid & 15;          // lane&15
  int q = (tid & 63) >> 4;   // quad
  int nbase = blockIdx.x * 64 + wv * 16;

  // A fragments: A[m=c][k=kk*32+q*8+j], u = [aggr | x] (bf16 direct)
  int na = min(nbase + c, kN - 1);
  bf16x8 afrag[4];
#pragma unroll
  for (int kk = 0; kk < 4; kk++) {
    const unsigned short* src = (kk < 2)
        ? aggr_b + (size_t)na * 64 + kk * 32 + q * 8
        : xb + (size_t)na * 64 + (kk - 2) * 32 + q * 8;
    U4BF t;
    t.u = *(const uint4*)src;
    afrag[kk] = t.v;
  }

  f32x4 acc[16];
#pragma unroll
  for (int jt = 0; jt < 16; jt++) {
    f32x4 a = {0.f, 0.f, 0.f, 0.f};
#pragma unroll
    for (int kk = 0; kk < 4; kk++) {
      const bf16x8* bp =
          (const bf16x8*)(Bt + (size_t)(jt * 16 + c) * 128 + kk * 32 + q * 8);
      a = __builtin_amdgcn_mfma_f32_16x16x32_bf16(afrag[kk], *bp, a, 0, 0, 0);
    }
    acc[jt] = a;
  }

  // Epilogue: node n = nbase + q*4 + reg, dim d = jt4*16 + c
  float s1[4] = {0.f, 0.f, 0.f, 0.f}, s2[4] = {0.f, 0.f, 0.f, 0.f};
#pragma unroll
  for (int jt4 = 0; jt4 < 4; jt4++) {
    int d = jt4 * 16 + c;
    float br = bih[d] + bhh[d];
    float bz = bih[64 + d] + bhh[64 + d];
    float bin = bih[128 + d];
    float bhn = bhh[128 + d];
    float rt = root[d];
#pragma unroll
    for (int reg = 0; reg < 4; reg++) {
      int n = nbase + q * 4 + reg;
      if (n < kN) {
        float xv = x[(size_t)n * 64 + d];
        float r = sigm(acc[jt4][reg] + br);
        float z = sigm(acc[4 + jt4][reg] + bz);
        float nn = tanh_f(acc[8 + jt4][reg] + bin + r * (acc[12 + jt4][reg] + bhn));
        float upd = (1.f - z) * nn + z * xv;
        float hl = upd + fmaxf(xv + rt, 0.f) / degf[n];
        h[(size_t)n * 64 + d] = hl;
        s1[jt4] += hl;
        s2[jt4] += hl * hl;
      }
    }
  }

  int rowi = wv * 4 + q;
#pragma unroll
  for (int jt4 = 0; jt4 < 4; jt4++) {
    sb[0][rowi][jt4 * 16 + c] = s1[jt4];
    sb[1][rowi][jt4 * 16 + c] = s2[jt4];
  }
  __syncthreads();
  if (tid < 64) {
    float t1 = 0.f, t2 = 0.f;
#pragma unroll
    for (int rr = 0; rr < 16; rr++) {
      t1 += sb[0][rr][tid];
      t2 += sb[1][rr][tid];
    }
    atomicAdd(&bnsum[tid], t1);
    atomicAdd(&bnss[tid], t2);
  }
}

// ---------- final BN (layer 2, no relu) -> d_out ----------
__global__ void k_final(const float* __restrict__ h, const float* __restrict__ bnsum,
                        const float* __restrict__ bnss, const float* __restrict__ bng,
                        const float* __restrict__ bnb, float* __restrict__ out) {
  int idx = blockIdx.x * blockDim.x + threadIdx.x;
  if (idx < kN * kD) {
    int d = idx & 63;
    float m = bnsum[d] * (1.f / (float)kN);
    float var = bnss[d] * (1.f / (float)kN) - m * m;
    float sc = rsqrtf(var + 1e-5f) * bng[d];
    out[idx] = (h[idx] - m) * sc + bnb[d];
  }
}

extern "C" void kernel_launch(void* const* d_in, const int* in_sizes, int n_in,
                              void* d_out, int out_size, void* d_ws, size_t ws_size,
                              hipStream_t stream) {
  const float* atom_x       = (const float*)d_in[0];
  const int*   atom_feature = (const int*)d_in[1];
  const int*   edge_index   = (const int*)d_in[2];
  const float* edge_attr    = (const float*)d_in[3];
  const float* atom_emb     = (const float*)d_in[4];
  const float* proj_W       = (const float*)d_in[5];
  const float* proj_b       = (const float*)d_in[6];
  const float* lin_W        = (const float*)d_in[7];
  const float* lin_b        = (const float*)d_in[8];
  const float* root_emb     = (const float*)d_in[9];
  const float* bond_W       = (const float*)d_in[10];
  const float* bond_b       = (const float*)d_in[11];
  const float* bond_g       = (const float*)d_in[12];
  const float* bond_beta    = (const float*)d_in[13];
  const float* gru_Wih      = (const float*)d_in[14];
  const float* gru_bih      = (const float*)d_in[15];
  const float* gru_Whh      = (const float*)d_in[16];
  const float* gru_bhh      = (const float*)d_in[17];
  const float* bn_g         = (const float*)d_in[18];
  const float* bn_b         = (const float*)d_in[19];
  float* out = (float*)d_out;

  const int* row = edge_index;
  const int* col = edge_index + kE;

  float* ws = (float*)d_ws;
  const size_t NH = (size_t)kN * kD;
  float* h     = ws;                         // NH
  float* x     = h + NH;                     // NH
  float* degf  = x + NH;                     // kN
  float* dinv  = degf + kN;                  // kN
  int*   cntr  = (int*)(dinv + kN);          // kN
  int*   cntc  = cntr + kN;                  // kN
  int*   ptr   = cntc + kN;                  // kN+1 (reserve kN+4, keeps align)
  int*   fill  = ptr + kN + 4;               // kN
  int*   loc   = fill + kN;                  // kN
  int*   bsum  = loc + kN;                   // 128
  int*   boff  = bsum + 128;                 // 128
  int2*  re    = (int2*)(boff + 128);        // kE int2
  float* nrm   = (float*)(re + kE);          // kE
  unsigned short* ea_s   = (unsigned short*)(nrm + kE);      // kE*16
  unsigned short* xb     = ea_s + (size_t)kE * 16;           // N*64
  unsigned short* aggr_b = xb + (size_t)kN * 64;             // N*64
  unsigned short* Bt     = aggr_b + (size_t)kN * 64;         // 3*256*128
  float* sumA  = (float*)(Bt + 3 * 256 * 128);  // 16
  float* Msum  = sumA + 16;                  // 256
  float* Weff  = Msum + 256;                 // 3*1024
  float* beff  = Weff + 3 * 1024;            // 192
  float* bnsum = beff + 192;                 // 64
  float* bnss  = bnsum + 64;                 // 64

  hipMemsetAsync(cntr, 0, 2 * kN * sizeof(int), stream);
  k_cnt<<<(kE + 255) / 256, 256, 0, stream>>>(row, col, cntr, cntc);
  k_dinv<<<(kN + 255) / 256, 256, 0, stream>>>(cntr, degf, dinv);
  k_scanA<<<kScanBlocks, 1024, 0, stream>>>(cntc, loc, bsum);
  k_scanB<<<1, 128, 0, stream>>>(bsum, boff);
  k_scanC<<<kScanBlocks, 1024, 0, stream>>>(loc, boff, ptr, fill);
  k_scatter<<<(kE + 255) / 256, 256, 0, stream>>>(row, col, dinv, fill, re, nrm);
  k_gea<<<(kE * 16 + 255) / 256, 256, 0, stream>>>(re, edge_attr, ea_s);

  hipMemsetAsync(sumA, 0, (16 + 256) * sizeof(float), stream);
  k_stats<<<512, 256, 0, stream>>>(edge_attr, sumA, Msum);
  k_bnfold<<<1, 256, 0, stream>>>(sumA, Msum, bond_W, bond_b, bond_g, bond_beta,
                                  Weff, beff);
  k_wprep<<<(3 * 256 * 128 + 255) / 256, 256, 0, stream>>>(gru_Wih, gru_Whh, Bt);
  k_enc<<<1024, 256, 0, stream>>>(atom_x, atom_feature, atom_emb, proj_W, proj_b, h);

  for (int l = 0; l < 3; l++) {
    const float* pg = (l > 0) ? (bn_g + (l - 1) * 64) : bn_g;
    const float* pb = (l > 0) ? (bn_b + (l - 1) * 64) : bn_b;
    k_lin<<<1024, 256, 0, stream>>>(h, lin_W + l * 64 * 64, lin_b + l * 64,
                                    l > 0 ? 1 : 0, bnsum, bnss, pg, pb, x, xb);
    k_aggr<<<(kN + 3) / 4, 256, 0, stream>>>(ptr, re, nrm, ea_s, xb,
                                             Weff + l * 1024, beff + l * 64, aggr_b);
    hipMemsetAsync(bnsum, 0, 128 * sizeof(float), stream);
    k_gru_mfma<<<(kN + 63) / 64, 256, 0, stream>>>(
        aggr_b, xb, x, Bt + (size_t)l * 256 * 128, gru_bih + l * 192,
        gru_bhh + l * 192, root_emb + l * 64, degf, h, bnsum, bnss);
  }
  k_final<<<(kN * kD + 255) / 256, 256, 0, stream>>>(h, bnsum, bnss, bn_g + 2 * 64,
                                                     bn_b + 2 * 64, out);
}

// Round 6
// 1452.225 us; speedup vs baseline: 1.0679x; 1.0679x over previous
//
#include <hip/hip_runtime.h>
#include <hip/hip_bf16.h>

constexpr int kN    = 100000;
constexpr int kE    = 1600000;
constexpr int kD    = 64;
constexpr int kNF   = 9;
constexpr int kCARD = 16;
constexpr int kBF   = 16;
constexpr int kScanBlocks = (kN + 1023) / 1024;  // 98

typedef __bf16 bf16x8 __attribute__((ext_vector_type(8)));
typedef float f32x4 __attribute__((ext_vector_type(4)));
union U4BF { uint4 u; bf16x8 v; };

__device__ __forceinline__ float lane_bcast(float v, int k) {
  return __uint_as_float((unsigned)__builtin_amdgcn_readlane((int)__float_as_uint(v), k));
}
__device__ __forceinline__ float sigm(float v) { return 1.f / (1.f + __expf(-v)); }
__device__ __forceinline__ float tanh_f(float v) { return 1.f - 2.f / (__expf(2.f * v) + 1.f); }

__device__ __forceinline__ unsigned bf16_bits(float v) {
  unsigned u = __float_as_uint(v);
  return (u + 0x7fffu + ((u >> 16) & 1u)) >> 16;
}

// ---------- degree counts (row for deg/dinv, col for CSR) ----------
__global__ void k_cnt(const int* __restrict__ row, const int* __restrict__ col,
                      int* __restrict__ cntr, int* __restrict__ cntc) {
  int e = blockIdx.x * blockDim.x + threadIdx.x;
  if (e < kE) {
    atomicAdd(&cntr[row[e]], 1);
    atomicAdd(&cntc[col[e]], 1);
  }
}

__global__ void k_dinv(const int* __restrict__ cnt, float* __restrict__ degf,
                       float* __restrict__ dinv) {
  int n = blockIdx.x * blockDim.x + threadIdx.x;
  if (n < kN) {
    float d = (float)cnt[n] + 1.f;
    degf[n] = d;
    dinv[n] = rsqrtf(d);
  }
}

// ---------- multi-block exclusive scan of col counts ----------
__global__ __launch_bounds__(1024) void k_scanA(const int* __restrict__ cnt,
                                                int* __restrict__ loc,
                                                int* __restrict__ bsum) {
  __shared__ int part[1024];
  int tid = threadIdx.x;
  int i = blockIdx.x * 1024 + tid;
  int v = (i < kN) ? cnt[i] : 0;
  part[tid] = v;
  __syncthreads();
  for (int off = 1; off < 1024; off <<= 1) {
    int t = (tid >= off) ? part[tid - off] : 0;
    __syncthreads();
    part[tid] += t;
    __syncthreads();
  }
  if (i < kN) loc[i] = part[tid] - v;  // local exclusive
  if (tid == 1023) bsum[blockIdx.x] = part[1023];
}

__global__ __launch_bounds__(128) void k_scanB(const int* __restrict__ bsum,
                                               int* __restrict__ boff) {
  __shared__ int p[128];
  int tid = threadIdx.x;
  int v = (tid < kScanBlocks) ? bsum[tid] : 0;
  p[tid] = v;
  __syncthreads();
  for (int off = 1; off < 128; off <<= 1) {
    int t = (tid >= off) ? p[tid - off] : 0;
    __syncthreads();
    p[tid] += t;
    __syncthreads();
  }
  boff[tid] = p[tid] - v;  // exclusive
}

__global__ __launch_bounds__(1024) void k_scanC(const int* __restrict__ loc,
                                                const int* __restrict__ boff,
                                                int* __restrict__ ptr,
                                                int* __restrict__ fill) {
  int i = blockIdx.x * 1024 + threadIdx.x;
  if (i < kN) {
    int v = loc[i] + boff[blockIdx.x];
    ptr[i] = v;
    fill[i] = v;
  }
  if (i == 0) ptr[kN] = kE;  // grand total is statically kE
}

// ---------- scatter (row, eid) + norm into col-sorted order ----------
__global__ void k_scatter(const int* __restrict__ row, const int* __restrict__ col,
                          const float* __restrict__ dinv, int* __restrict__ fill,
                          int2* __restrict__ re, float* __restrict__ nrm) {
  int e = blockIdx.x * blockDim.x + threadIdx.x;
  if (e < kE) {
    int r = row[e], c = col[e];
    int p = atomicAdd(&fill[c], 1);
    re[p] = make_int2(r, e);
    nrm[p] = dinv[r] * dinv[c];
  }
}

// ---------- reorder edge_attr into CSR order as bf16 (16 thr/edge) ----------
__global__ void k_gea(const int2* __restrict__ re, const float* __restrict__ ea,
                      unsigned short* __restrict__ ea_s) {
  int idx = blockIdx.x * 256 + threadIdx.x;
  int p = idx >> 4, c = idx & 15;
  if (p < kE) {
    int e = re[p].y;
    ea_s[(size_t)p * 16 + c] = (unsigned short)bf16_bits(ea[(size_t)e * 16 + c]);
  }
}

// ---------- edge_attr moments: sumA[16], M = A^T A [16x16] ----------
__global__ __launch_bounds__(256) void k_stats(const float* __restrict__ ea,
                                               float* __restrict__ sumA,
                                               float* __restrict__ Msum) {
  __shared__ float tile[1024];
  int tid = threadIdx.x;
  int i = tid >> 4, j = tid & 15;
  float accM = 0.f, accS = 0.f;
  const int T = kE / 64;
  for (int t = blockIdx.x; t < T; t += gridDim.x) {
    const float4* src = (const float4*)(ea + (size_t)t * 1024);
    ((float4*)tile)[tid] = src[tid];
    __syncthreads();
#pragma unroll 8
    for (int e = 0; e < 64; e++) {
      float aj = tile[e * 16 + j];
      accM += tile[e * 16 + i] * aj;
      if (i == 0) accS += aj;
    }
    __syncthreads();
  }
  atomicAdd(&Msum[i * 16 + j], accM);
  if (i == 0) atomicAdd(&sumA[j], accS);
}

// ---------- fold bond-linear + BN into WeffbT (bf16, [l][d][k]) + beff ----------
__global__ __launch_bounds__(256) void k_bnfold(
    const float* __restrict__ sumA, const float* __restrict__ Msum,
    const float* __restrict__ bond_W, const float* __restrict__ bond_b,
    const float* __restrict__ bond_g, const float* __restrict__ bond_beta,
    unsigned short* __restrict__ WeffbT, float* __restrict__ beff) {
  __shared__ float Ms[256];
  __shared__ float ab[16];
  int tid = threadIdx.x;
  Ms[tid] = Msum[tid] * (1.f / (float)kE);
  if (tid < 16) ab[tid] = sumA[tid] * (1.f / (float)kE);
  __syncthreads();
  if (tid < 192) {
    int l = tid / 64, d = tid % 64;
    const float* W = bond_W + l * kBF * kD;
    float w[16];
#pragma unroll
    for (int k = 0; k < 16; k++) w[k] = W[k * 64 + d];
    float b = bond_b[l * 64 + d];
    float lin = 0.f;
#pragma unroll
    for (int k = 0; k < 16; k++) lin += ab[k] * w[k];
    float mu = lin + b;
    float q = 0.f;
#pragma unroll
    for (int i = 0; i < 16; i++) {
      float wi = w[i];
#pragma unroll
      for (int k = 0; k < 16; k++) q += Ms[i * 16 + k] * wi * w[k];
    }
    float ex2 = q + 2.f * b * lin + b * b;
    float var = ex2 - mu * mu;
    float s = bond_g[l * 64 + d] * rsqrtf(var + 1e-6f);
#pragma unroll
    for (int k = 0; k < 16; k++)
      WeffbT[(size_t)(l * 64 + d) * 16 + k] = (unsigned short)bf16_bits(w[k] * s);
    beff[l * 64 + d] = (b - mu) * s + bond_beta[l * 64 + d];
  }
}

// ---------- GRU weight prep: Bt[l][j][k] bf16, j in [0,256), k in [0,128) ----------
__global__ void k_wprep(const float* __restrict__ Wih, const float* __restrict__ Whh,
                        unsigned short* __restrict__ Bt) {
  int idx = blockIdx.x * 256 + threadIdx.x;
  if (idx >= 3 * 256 * 128) return;
  int l = idx / (256 * 128);
  int rem = idx % (256 * 128);
  int j = rem / 128, k = rem % 128;
  const float* ih = Wih + l * 192 * 64;
  const float* hh = Whh + l * 192 * 64;
  float v;
  if (j < 128)      v = (k < 64) ? ih[j * 64 + k] : hh[j * 64 + (k - 64)];
  else if (j < 192) v = (k < 64) ? ih[j * 64 + k] : 0.f;
  else              v = (k < 64) ? 0.f : hh[(j - 64) * 64 + (k - 64)];
  Bt[idx] = (unsigned short)bf16_bits(v);
}

// ---------- encoder: h = [atom_x, sum_f emb] @ projW + b ----------
__global__ __launch_bounds__(256) void k_enc(
    const float* __restrict__ atom_x, const int* __restrict__ feat,
    const float* __restrict__ emb, const float* __restrict__ projW,
    const float* __restrict__ projb, float* __restrict__ h) {
  __shared__ float W[128 * 64];
  int tid = threadIdx.x;
  for (int i = tid; i < 128 * 64 / 4; i += 256)
    ((float4*)W)[i] = ((const float4*)projW)[i];
  __syncthreads();
  int lane = tid & 63, wv = tid >> 6;
  int gw = blockIdx.x * 4 + wv, nw = gridDim.x * 4;
  float bd = projb[lane];
  for (int grp = gw; grp < kN / 4; grp += nw) {
    int n0 = grp * 4;
    float ax[4], x2[4], acc[4];
#pragma unroll
    for (int i = 0; i < 4; i++) {
      int n = n0 + i;
      ax[i] = atom_x[n * kD + lane];
      const int* fr = feat + n * kNF;
      float s = 0.f;
#pragma unroll
      for (int f = 0; f < kNF; f++) {
        int c = fr[f];
        s += emb[(f * kCARD + c) * kD + lane];
      }
      x2[i] = s;
      acc[i] = bd;
    }
#pragma unroll 4
    for (int k = 0; k < kD; k++) {
      float wt = W[k * 64 + lane];
      float wb = W[(64 + k) * 64 + lane];
#pragma unroll
      for (int i = 0; i < 4; i++)
        acc[i] += lane_bcast(ax[i], k) * wt + lane_bcast(x2[i], k) * wb;
    }
#pragma unroll
    for (int i = 0; i < 4; i++) h[(n0 + i) * kD + lane] = acc[i];
  }
}

// ---------- x = BN(h)[opt relu] @ lin_W + lin_b ; writes fp32 x and bf16 xb ----------
__global__ __launch_bounds__(256) void k_lin(
    const float* __restrict__ hin, const float* __restrict__ Wg,
    const float* __restrict__ bg, int apply_bn,
    const float* __restrict__ bnsum, const float* __restrict__ bnss,
    const float* __restrict__ bng, const float* __restrict__ bnb,
    float* __restrict__ xout, unsigned short* __restrict__ xb) {
  __shared__ float W[64 * 64];
  int tid = threadIdx.x;
  for (int i = tid; i < 64 * 64 / 4; i += 256)
    ((float4*)W)[i] = ((const float4*)Wg)[i];
  __syncthreads();
  int lane = tid & 63, wv = tid >> 6;
  int gw = blockIdx.x * 4 + wv, nw = gridDim.x * 4;
  float mu = 0.f, sc = 0.f, bb = 0.f;
  if (apply_bn) {
    float m = bnsum[lane] * (1.f / (float)kN);
    float var = bnss[lane] * (1.f / (float)kN) - m * m;
    mu = m;
    sc = rsqrtf(var + 1e-5f) * bng[lane];
    bb = bnb[lane];
  }
  float bd = bg[lane];
  for (int grp = gw; grp < kN / 4; grp += nw) {
    int n0 = grp * 4;
    float hv[4], acc[4];
#pragma unroll
    for (int i = 0; i < 4; i++) {
      float v = hin[(n0 + i) * kD + lane];
      if (apply_bn) v = fmaxf((v - mu) * sc + bb, 0.f);
      hv[i] = v;
      acc[i] = bd;
    }
#pragma unroll 4
    for (int k = 0; k < kD; k++) {
      float w = W[k * 64 + lane];
#pragma unroll
      for (int i = 0; i < 4; i++) acc[i] += lane_bcast(hv[i], k) * w;
    }
#pragma unroll
    for (int i = 0; i < 4; i++) {
      xout[(n0 + i) * kD + lane] = acc[i];
      xb[(size_t)(n0 + i) * kD + lane] = (unsigned short)bf16_bits(acc[i]);
    }
  }
}

// ---------- CSR gather with MFMA bond: one wave per node ----------
// bond[16e,64d] = ea_tile @ Weff via 4x mfma_16x16x32 (K=16 zero-padded)
__global__ __launch_bounds__(256) void k_aggr(
    const int* __restrict__ ptr, const int2* __restrict__ re,
    const float* __restrict__ nrm, const unsigned short* __restrict__ ea_s,
    const unsigned short* __restrict__ xb, const unsigned short* __restrict__ WeffbT,
    const float* __restrict__ beff, unsigned short* __restrict__ aggr_b) {
  int lane = threadIdx.x & 63, wv = threadIdx.x >> 6;
  int n = blockIdx.x * 4 + wv;
  if (n >= kN) return;
  int c = lane & 15, q = lane >> 4;

  U4BF z; z.u = make_uint4(0u, 0u, 0u, 0u);
  // B frags: B[k=q*8+j][n=nt*16+c] = Weff[k][d]; WeffbT stored [d][k]
  bf16x8 bfr[4];
#pragma unroll
  for (int nt = 0; nt < 4; nt++) {
    if (q < 2) {
      U4BF t;
      t.u = *(const uint4*)(WeffbT + (size_t)(nt * 16 + c) * 16 + q * 8);
      bfr[nt] = t.v;
    } else {
      bfr[nt] = z.v;
    }
  }
  float be4[4];
#pragma unroll
  for (int nt = 0; nt < 4; nt++) be4[nt] = beff[nt * 16 + c];

  int start = ptr[n], end = ptr[n + 1];
  float pacc[4] = {0.f, 0.f, 0.f, 0.f};  // dims nt*16+c, partial over quad q's edges

  for (int j0 = start; j0 < end; j0 += 64) {
    int j = j0 + lane;
    bool val = j < end;
    int2 m = val ? re[j] : make_int2(0, 0);
    float nr = val ? nrm[j] : 0.f;
    int cnt = min(64, end - j0);
    int mts = (cnt + 15) >> 4;
    for (int mt = 0; mt < mts; mt++) {
      // A frag: A[m=c][k=q*8+j] from edge (j0 + mt*16 + c); zero for k>=16
      bf16x8 afr;
      if (q < 2) {
        U4BF t;
        t.u = *(const uint4*)(ea_s + (size_t)(j0 + mt * 16 + c) * 16 + q * 8);
        afr = t.v;
      } else {
        afr = z.v;
      }
      f32x4 bond[4];
#pragma unroll
      for (int nt = 0; nt < 4; nt++) {
        f32x4 a = {0.f, 0.f, 0.f, 0.f};
        bond[nt] = __builtin_amdgcn_mfma_f32_16x16x32_bf16(afr, bfr[nt], a, 0, 0, 0);
      }
      // epilogue: C row = q*4+reg -> local edge el = mt*16 + q*4 + reg
#pragma unroll
      for (int reg = 0; reg < 4; reg++) {
        int el = mt * 16 + (q << 2) + reg;
        int rt = __builtin_amdgcn_ds_bpermute(el << 2, m.x);
        float nv = __uint_as_float(
            (unsigned)__builtin_amdgcn_ds_bpermute(el << 2, (int)__float_as_uint(nr)));
        const unsigned short* xr = xb + (size_t)rt * 64;
#pragma unroll
        for (int nt = 0; nt < 4; nt++) {
          float xv = __uint_as_float(((unsigned)xr[nt * 16 + c]) << 16);
          pacc[nt] += nv * fmaxf(xv + bond[nt][reg] + be4[nt], 0.f);
        }
      }
    }
  }
  // reduce partials across quads (lanes c, c+16, c+32, c+48 share dim nt*16+c)
#pragma unroll
  for (int nt = 0; nt < 4; nt++) {
    pacc[nt] += __shfl_xor(pacc[nt], 16, 64);
    pacc[nt] += __shfl_xor(pacc[nt], 32, 64);
  }
  // lane (q,c) writes dim q*16+c == its own lane index
  float outv = (q == 0) ? pacc[0] : (q == 1) ? pacc[1] : (q == 2) ? pacc[2] : pacc[3];
  aggr_b[(size_t)n * 64 + lane] = (unsigned short)bf16_bits(outv);
}

// ---------- MFMA GRU, register-blocked B: wave w = dim chunk, all 4 gates ----------
__global__ __launch_bounds__(256) void k_gru_mfma(
    const unsigned short* __restrict__ aggr_b, const unsigned short* __restrict__ xb,
    const float* __restrict__ x, const unsigned short* __restrict__ Bt,
    const float* __restrict__ bih, const float* __restrict__ bhh,
    const float* __restrict__ root, const float* __restrict__ degf,
    float* __restrict__ h, float* __restrict__ bnsum, float* __restrict__ bnss) {
  int tid = threadIdx.x;
  int w = tid >> 6;          // dim chunk (jt4)
  int lane = tid & 63;
  int c = lane & 15, q = lane >> 4;
  int nbase = blockIdx.x * 128;
  int d = w * 16 + c;

  // B frags for gates g: output col = (g*4+w)*16 + c; loaded ONCE, reused 8x
  bf16x8 bfr[4][4];
#pragma unroll
  for (int g = 0; g < 4; g++)
#pragma unroll
    for (int kk = 0; kk < 4; kk++) {
      U4BF t;
      t.u = *(const uint4*)(Bt + (size_t)((g * 4 + w) * 16 + c) * 128 + kk * 32 + q * 8);
      bfr[g][kk] = t.v;
    }

  float br = bih[d] + bhh[d];
  float bz = bih[64 + d] + bhh[64 + d];
  float bin = bih[128 + d];
  float bhn = bhh[128 + d];
  float rt = root[d];
  float s1 = 0.f, s2 = 0.f;

#pragma unroll 2
  for (int mt = 0; mt < 8; mt++) {
    int na = nbase + mt * 16 + c;
    int nac = min(na, kN - 1);
    bf16x8 afr[4];
#pragma unroll
    for (int kk = 0; kk < 4; kk++) {
      const unsigned short* src = (kk < 2)
          ? aggr_b + (size_t)nac * 64 + kk * 32 + q * 8
          : xb + (size_t)nac * 64 + (kk - 2) * 32 + q * 8;
      U4BF t;
      t.u = *(const uint4*)src;
      afr[kk] = t.v;
    }
    f32x4 acc[4];
#pragma unroll
    for (int g = 0; g < 4; g++) {
      f32x4 a = {0.f, 0.f, 0.f, 0.f};
#pragma unroll
      for (int kk = 0; kk < 4; kk++)
        a = __builtin_amdgcn_mfma_f32_16x16x32_bf16(afr[kk], bfr[g][kk], a, 0, 0, 0);
      acc[g] = a;
    }
#pragma unroll
    for (int reg = 0; reg < 4; reg++) {
      int n = nbase + mt * 16 + q * 4 + reg;
      if (n < kN) {
        float xv = x[(size_t)n * 64 + d];
        float r = sigm(acc[0][reg] + br);
        float zz = sigm(acc[1][reg] + bz);
        float nn = tanh_f(acc[2][reg] + bin + r * (acc[3][reg] + bhn));
        float upd = (1.f - zz) * nn + zz * xv;
        float hl = upd + fmaxf(xv + rt, 0.f) / degf[n];
        h[(size_t)n * 64 + d] = hl;
        s1 += hl;
        s2 += hl * hl;
      }
    }
  }
  // BN partials: lanes with same (w,c) across q hold same dim d over disjoint nodes
  s1 += __shfl_xor(s1, 16, 64);
  s1 += __shfl_xor(s1, 32, 64);
  s2 += __shfl_xor(s2, 16, 64);
  s2 += __shfl_xor(s2, 32, 64);
  if (q == 0) {
    atomicAdd(&bnsum[d], s1);
    atomicAdd(&bnss[d], s2);
  }
}

// ---------- final BN (layer 2, no relu) -> d_out ----------
__global__ void k_final(const float* __restrict__ h, const float* __restrict__ bnsum,
                        const float* __restrict__ bnss, const float* __restrict__ bng,
                        const float* __restrict__ bnb, float* __restrict__ out) {
  int idx = blockIdx.x * blockDim.x + threadIdx.x;
  if (idx < kN * kD) {
    int d = idx & 63;
    float m = bnsum[d] * (1.f / (float)kN);
    float var = bnss[d] * (1.f / (float)kN) - m * m;
    float sc = rsqrtf(var + 1e-5f) * bng[d];
    out[idx] = (h[idx] - m) * sc + bnb[d];
  }
}

extern "C" void kernel_launch(void* const* d_in, const int* in_sizes, int n_in,
                              void* d_out, int out_size, void* d_ws, size_t ws_size,
                              hipStream_t stream) {
  const float* atom_x       = (const float*)d_in[0];
  const int*   atom_feature = (const int*)d_in[1];
  const int*   edge_index   = (const int*)d_in[2];
  const float* edge_attr    = (const float*)d_in[3];
  const float* atom_emb     = (const float*)d_in[4];
  const float* proj_W       = (const float*)d_in[5];
  const float* proj_b       = (const float*)d_in[6];
  const float* lin_W        = (const float*)d_in[7];
  const float* lin_b        = (const float*)d_in[8];
  const float* root_emb     = (const float*)d_in[9];
  const float* bond_W       = (const float*)d_in[10];
  const float* bond_b       = (const float*)d_in[11];
  const float* bond_g       = (const float*)d_in[12];
  const float* bond_beta    = (const float*)d_in[13];
  const float* gru_Wih      = (const float*)d_in[14];
  const float* gru_bih      = (const float*)d_in[15];
  const float* gru_Whh      = (const float*)d_in[16];
  const float* gru_bhh      = (const float*)d_in[17];
  const float* bn_g         = (const float*)d_in[18];
  const float* bn_b         = (const float*)d_in[19];
  float* out = (float*)d_out;

  const int* row = edge_index;
  const int* col = edge_index + kE;

  float* ws = (float*)d_ws;
  const size_t NH = (size_t)kN * kD;
  float* h     = ws;                         // NH
  float* x     = h + NH;                     // NH
  float* degf  = x + NH;                     // kN
  float* dinv  = degf + kN;                  // kN
  int*   cntr  = (int*)(dinv + kN);          // kN
  int*   cntc  = cntr + kN;                  // kN
  int*   ptr   = cntc + kN;                  // kN+1 (reserve kN+4)
  int*   fill  = ptr + kN + 4;               // kN
  int*   loc   = fill + kN;                  // kN
  int*   bsum  = loc + kN;                   // 128
  int*   boff  = bsum + 128;                 // 128
  int2*  re    = (int2*)(boff + 128);        // kE int2
  float* nrm   = (float*)(re + kE);          // kE
  unsigned short* ea_s   = (unsigned short*)(nrm + kE);      // kE*16 + 1024 pad
  unsigned short* xb     = ea_s + (size_t)kE * 16 + 1024;    // N*64
  unsigned short* aggr_b = xb + (size_t)kN * 64;             // N*64
  unsigned short* Bt     = aggr_b + (size_t)kN * 64;         // 3*256*128
  unsigned short* WeffbT = Bt + 3 * 256 * 128;               // 3*64*16
  float* sumA  = (float*)(WeffbT + 3 * 64 * 16);  // 16
  float* Msum  = sumA + 16;                  // 256
  float* beff  = Msum + 256;                 // 192
  float* bnsum = beff + 192;                 // 64
  float* bnss  = bnsum + 64;                 // 64

  hipMemsetAsync(cntr, 0, 2 * kN * sizeof(int), stream);
  k_cnt<<<(kE + 255) / 256, 256, 0, stream>>>(row, col, cntr, cntc);
  k_dinv<<<(kN + 255) / 256, 256, 0, stream>>>(cntr, degf, dinv);
  k_scanA<<<kScanBlocks, 1024, 0, stream>>>(cntc, loc, bsum);
  k_scanB<<<1, 128, 0, stream>>>(bsum, boff);
  k_scanC<<<kScanBlocks, 1024, 0, stream>>>(loc, boff, ptr, fill);
  k_scatter<<<(kE + 255) / 256, 256, 0, stream>>>(row, col, dinv, fill, re, nrm);
  k_gea<<<(kE * 16 + 255) / 256, 256, 0, stream>>>(re, edge_attr, ea_s);

  hipMemsetAsync(sumA, 0, (16 + 256) * sizeof(float), stream);
  k_stats<<<512, 256, 0, stream>>>(edge_attr, sumA, Msum);
  k_bnfold<<<1, 256, 0, stream>>>(sumA, Msum, bond_W, bond_b, bond_g, bond_beta,
                                  WeffbT, beff);
  k_wprep<<<(3 * 256 * 128 + 255) / 256, 256, 0, stream>>>(gru_Wih, gru_Whh, Bt);
  k_enc<<<1024, 256, 0, stream>>>(atom_x, atom_feature, atom_emb, proj_W, proj_b, h);

  for (int l = 0; l < 3; l++) {
    const float* pg = (l > 0) ? (bn_g + (l - 1) * 64) : bn_g;
    const float* pb = (l > 0) ? (bn_b + (l - 1) * 64) : bn_b;
    k_lin<<<1024, 256, 0, stream>>>(h, lin_W + l * 64 * 64, lin_b + l * 64,
                                    l > 0 ? 1 : 0, bnsum, bnss, pg, pb, x, xb);
    k_aggr<<<(kN + 3) / 4, 256, 0, stream>>>(ptr, re, nrm, ea_s, xb,
                                             WeffbT + (size_t)l * 64 * 16,
                                             beff + l * 64, aggr_b);
    hipMemsetAsync(bnsum, 0, 128 * sizeof(float), stream);
    k_gru_mfma<<<(kN + 127) / 128, 256, 0, stream>>>(
        aggr_b, xb, x, Bt + (size_t)l * 256 * 128, gru_bih + l * 192,
        gru_bhh + l * 192, root_emb + l * 64, degf, h, bnsum, bnss);
  }
  k_final<<<(kN * kD + 255) / 256, 256, 0, stream>>>(h, bnsum, bnss, bn_g + 2 * 64,
                                                     bn_b + 2 * 64, out);
}